// Round 12
// baseline (258.572 us; speedup 1.0000x reference)
//
#include <hip/hip_runtime.h>

#define N_NODES 50000
#define N_EDGES 800000
#define IN_DIM  256
#define OUT_DIM 64
#define NB      196               // ceil(N_NODES/256)
#define CHUNK   4096
#define NCHUNK  196               // ceil(N_EDGES/CHUNK)

// --- d_ws byte layout (16B-aligned) ----------------------------------------
#define WS_SUPPORT 0              // 12,800,000 B
#define WS_COUNTS  12800000
#define WS_OFFSETS 13000064
#define WS_CURSOR  13200128
#define WS_BSUM    13400128
#define WS_BOFF    13400960
#define WS_RECS    13401792       // 800000 * 8 B
// total ~19.8 MB

// ---------------------------------------------------------------------------
// Kernel 1 (v3): support = input @ W with NO LDS. Per 64-k chunk each thread
// bulk-loads its row's 64 x into VGPRs (16 x global_load_dwordx4 -> VMCNT,
// in-order); W rides the wave-uniform scalar path (s_load_dwordx8 -> LGKMCNT
// carrying ONLY homogeneous s_loads -> compiler batch-pipelines them). The
// R8/R11 counters showed mixing ds_read+s_load on lgkmcnt serialized the
// loop (57.8us at 2 different occupancies). Inner loop: pure s_load + FMA.
// Each thread's 4 consecutive 64B lines are fully consumed by its own 16
// loads (MSHR-merged) -> no over-fetch; X is L3-resident (FETCH 25MB).
// ---------------------------------------------------------------------------
__global__ __launch_bounds__(256) void gcn_gemm(const float* __restrict__ input,
                                                const float* __restrict__ W,
                                                float* __restrict__ support)
{
    const int tid  = threadIdx.x;
    const int lane = tid & 63;
    const int gw   = __builtin_amdgcn_readfirstlane(
                         (int)((blockIdx.x * 256 + tid) >> 6));
    const int rg   = gw >> 3;          // row group (0..781), wave-uniform
    const int c0   = (gw & 7) * 8;     // first output col, wave-uniform
    if (rg >= (N_NODES + 63) / 64) return;

    int row = rg * 64 + lane;
    const int rowc = row < N_NODES ? row : N_NODES - 1;   // clamp for loads
    const float* xp = input + (size_t)rowc * IN_DIM;
    const float* Wc = W + c0;          // wave-uniform base -> s_load path

    float acc[8] = {0.f,0.f,0.f,0.f,0.f,0.f,0.f,0.f};

    for (int kc = 0; kc < 4; ++kc) {
        // bulk x-chunk load: 64 floats into VGPRs (VMCNT, in-order returns)
        float4 xv[16];
        #pragma unroll
        for (int f = 0; f < 16; ++f)
            xv[f] = *(const float4*)(xp + kc * 64 + f * 4);
        const float* Wk = Wc + (size_t)(kc * 64) * OUT_DIM;
        #pragma unroll
        for (int k6 = 0; k6 < 64; ++k6) {
            const float x = ((const float*)xv)[k6];        // static idx (unrolled)
            const float* wrow = Wk + (size_t)k6 * OUT_DIM; // uniform -> s_load
            #pragma unroll
            for (int j = 0; j < 8; ++j)
                acc[j] += x * wrow[j];
        }
    }

    if (row < N_NODES) {
        float* op = support + (size_t)row * OUT_DIM + c0;
        *(float4*)(op)     = make_float4(acc[0], acc[1], acc[2], acc[3]);
        *(float4*)(op + 4) = make_float4(acc[4], acc[5], acc[6], acc[7]);
    }
}

// ---------------------------------------------------------------------------
// Kernel 2: histogram of dst (counts pre-zeroed by hipMemsetAsync)
// ---------------------------------------------------------------------------
__global__ __launch_bounds__(256) void gcn_hist(const int* __restrict__ dst,
                                                int* __restrict__ counts)
{
    const int e = blockIdx.x * 256 + threadIdx.x;
    if (e < N_EDGES) atomicAdd(&counts[dst[e]], 1);
}

// ---------------------------------------------------------------------------
// Kernels 3a/3b/3c: hierarchical exclusive scan of counts -> offsets, cursor
// ---------------------------------------------------------------------------
__global__ __launch_bounds__(256) void gcn_scanA(const int* __restrict__ counts,
                                                 int* __restrict__ bsum)
{
    __shared__ int wsum[4];
    const int tid = threadIdx.x, lane = tid & 63, wid = tid >> 6;
    const int i = blockIdx.x * 256 + tid;
    int v = (i < N_NODES) ? counts[i] : 0;
    #pragma unroll
    for (int d = 32; d > 0; d >>= 1) v += __shfl_down(v, d);
    if (lane == 0) wsum[wid] = v;
    __syncthreads();
    if (tid == 0) bsum[blockIdx.x] = wsum[0] + wsum[1] + wsum[2] + wsum[3];
}

__global__ __launch_bounds__(256) void gcn_scanB(const int* __restrict__ bsum,
                                                 int* __restrict__ boff)
{
    __shared__ int wsum[4];
    const int tid = threadIdx.x, lane = tid & 63, wid = tid >> 6;
    const int orig = (tid < NB) ? bsum[tid] : 0;
    int v = orig;
    #pragma unroll
    for (int d = 1; d < 64; d <<= 1) {
        const int u = __shfl_up(v, d);
        if (lane >= d) v += u;
    }
    if (lane == 63) wsum[wid] = v;
    __syncthreads();
    int pre = 0;
    for (int ww = 0; ww < wid; ++ww) pre += wsum[ww];
    if (tid < NB) boff[tid] = pre + v - orig;
}

__global__ __launch_bounds__(256) void gcn_scanC(const int* __restrict__ counts,
                                                 const int* __restrict__ boff,
                                                 int* __restrict__ offsets,
                                                 int* __restrict__ cursor)
{
    __shared__ int wsum[4];
    const int tid = threadIdx.x, lane = tid & 63, wid = tid >> 6;
    const int i = blockIdx.x * 256 + tid;
    const int orig = (i < N_NODES) ? counts[i] : 0;
    int v = orig;
    #pragma unroll
    for (int d = 1; d < 64; d <<= 1) {
        const int u = __shfl_up(v, d);
        if (lane >= d) v += u;
    }
    if (lane == 63) wsum[wid] = v;
    __syncthreads();
    int pre = boff[blockIdx.x];
    for (int ww = 0; ww < wid; ++ww) pre += wsum[ww];
    const int excl = pre + v - orig;
    if (i < N_NODES) { offsets[i] = excl; cursor[i] = excl; }
    if (i == N_NODES - 1) offsets[N_NODES] = excl + orig;
}

// ---------------------------------------------------------------------------
// Kernel 4 (v2): slice-partitioned scatter. Block idx: chunk = idx>>3,
// slice = idx&7 (dst range of 6250 nodes). Consecutive blockIdx round-robin
// across the 8 XCDs -> all writers of a slice's recs lines share one XCD L2
// (slice recs ~800KB fits 4MB) -> each 64B line written back ~once instead
// of 8x (R8/R11 measured WRITE_SIZE 52MB for a 6.4MB buffer). Costs 8x edge
// re-reads (L3-resident). Correct regardless of the XCD mapping.
// slice(d) = (d*21475)>>27 == d/6250 for d<50000 (verified at boundaries).
// ---------------------------------------------------------------------------
__global__ __launch_bounds__(256) void gcn_build(const int*   __restrict__ src,
                                                 const int*   __restrict__ dst,
                                                 const float* __restrict__ val,
                                                 int*  __restrict__ cursor,
                                                 int2* __restrict__ recs)
{
    const int s  = blockIdx.x & 7;
    const int e0 = (blockIdx.x >> 3) * CHUNK;
    #pragma unroll 4
    for (int t = threadIdx.x; t < CHUNK; t += 256) {
        const int e = e0 + t;
        if (e < N_EDGES) {
            const int d = dst[e];
            if (((d * 21475) >> 27) == s) {
                const int pos = atomicAdd(&cursor[d], 1);
                recs[pos] = make_int2(src[e], __float_as_int(val[e]));
            }
        }
    }
}

// ---------------------------------------------------------------------------
// Kernel 5: per-node gather-accumulate, bias fused, no atomics.
// 4-deep rotating prefetch with NAMED registers (rule #20); readfirstlane(n)
// -> offsets/recs on the scalar path.
// ---------------------------------------------------------------------------
__global__ __launch_bounds__(256) void gcn_gather(const float* __restrict__ support,
                                                  const int2*  __restrict__ recs,
                                                  const int*   __restrict__ offsets,
                                                  const float* __restrict__ bias,
                                                  float* __restrict__ out)
{
    const int lane = threadIdx.x & 63;
    const int n = __builtin_amdgcn_readfirstlane(
                      (int)((blockIdx.x * 256 + threadIdx.x) >> 6));
    if (n >= N_NODES) return;

    const float b   = bias[lane];
    const int   beg = offsets[n];
    const int   end = offsets[n + 1];
    float acc = 0.f;
    int i = beg;

    if (end - beg >= 8) {
        int2 ra = recs[i],   rb = recs[i+1], rc = recs[i+2], rd = recs[i+3];
        float sa = support[(size_t)ra.x * OUT_DIM + lane];
        float sb = support[(size_t)rb.x * OUT_DIM + lane];
        float sc = support[(size_t)rc.x * OUT_DIM + lane];
        float sd = support[(size_t)rd.x * OUT_DIM + lane];
        for (; i + 8 <= end; i += 4) {
            const int2 na = recs[i+4], nb = recs[i+5], nc = recs[i+6], nd = recs[i+7];
            const float ta = support[(size_t)na.x * OUT_DIM + lane];
            const float tb = support[(size_t)nb.x * OUT_DIM + lane];
            const float tc = support[(size_t)nc.x * OUT_DIM + lane];
            const float td = support[(size_t)nd.x * OUT_DIM + lane];
            acc += __int_as_float(ra.y) * sa;
            acc += __int_as_float(rb.y) * sb;
            acc += __int_as_float(rc.y) * sc;
            acc += __int_as_float(rd.y) * sd;
            ra = na; sa = ta;  rb = nb; sb = tb;
            rc = nc; sc = tc;  rd = nd; sd = td;
        }
        acc += __int_as_float(ra.y) * sa + __int_as_float(rb.y) * sb
             + __int_as_float(rc.y) * sc + __int_as_float(rd.y) * sd;
        i += 4;
    }
    for (; i < end; ++i) {
        const int2 r = recs[i];
        acc += __int_as_float(r.y) * support[(size_t)r.x * OUT_DIM + lane];
    }
    out[(size_t)n * OUT_DIM + lane] = acc + b;
}

// ---------------------------------------------------------------------------
extern "C" void kernel_launch(void* const* d_in, const int* in_sizes, int n_in,
                              void* d_out, int out_size, void* d_ws, size_t ws_size,
                              hipStream_t stream)
{
    const float* input  = (const float*)d_in[0];
    const float* weight = (const float*)d_in[1];
    const float* bias   = (const float*)d_in[2];
    const float* eval_  = (const float*)d_in[3];
    const int*   esrc   = (const int*)d_in[4];
    const int*   edst   = (const int*)d_in[5];
    float*       out    = (float*)d_out;

    char* ws = (char*)d_ws;
    float* support = (float*)(ws + WS_SUPPORT);
    int*   counts  = (int*)(ws + WS_COUNTS);
    int*   offsets = (int*)(ws + WS_OFFSETS);
    int*   cursor  = (int*)(ws + WS_CURSOR);
    int*   bsum    = (int*)(ws + WS_BSUM);
    int*   boff    = (int*)(ws + WS_BOFF);
    int2*  recs    = (int2*)(ws + WS_RECS);

    hipMemsetAsync(counts, 0, N_NODES * sizeof(int), stream);

    // support = X @ W   (6256 waves = 1564 blocks x 4 waves)
    gcn_gemm<<<1564, 256, 0, stream>>>(input, weight, support);

    // fine CSR-by-dst build
    gcn_hist <<<(N_EDGES + 255) / 256, 256, 0, stream>>>(edst, counts);
    gcn_scanA<<<NB, 256, 0, stream>>>(counts, bsum);
    gcn_scanB<<<1, 256, 0, stream>>>(bsum, boff);
    gcn_scanC<<<NB, 256, 0, stream>>>(counts, boff, offsets, cursor);
    gcn_build<<<NCHUNK * 8, 256, 0, stream>>>(esrc, edst, eval_, cursor, recs);

    // out[n] = sum_{e: dst=n} val_e * support[src_e] + bias
    gcn_gather<<<(N_NODES * 64) / 256, 256, 0, stream>>>(support, recs, offsets, bias, out);
}